// Round 18
// baseline (232.472 us; speedup 1.0000x reference)
//
#include <hip/hip_runtime.h>
#include <math.h>

#define DIM 64
#define NEG_SLOPE 0.01f
#define NBMAX 1024

typedef unsigned short bfraw;
typedef unsigned int uint32;

__device__ __forceinline__ bfraw f2bf(float f) {
    unsigned int u = __float_as_uint(f);
    unsigned int r = (u + 0x7FFFu + ((u >> 16) & 1u)) >> 16;  // RNE
    return (bfraw)r;
}
__device__ __forceinline__ float bflo(uint32 u) { return __uint_as_float(u << 16); }
__device__ __forceinline__ float bfhi(uint32 u) { return __uint_as_float(u & 0xFFFF0000u); }
__device__ __forceinline__ uint32 pack2(float lo, float hi) {
    return (uint32)f2bf(lo) | ((uint32)f2bf(hi) << 16);
}

// ---------------- bin packed records ((local_dst<<sbits)|src) into fixed-cap bucket regions ----------------
#define EPW 4096

__global__ __launch_bounds__(256) void k_bin(const int* __restrict__ ei, int E,
                                             uint32* __restrict__ stage,
                                             int* __restrict__ bcur, int shift, int sbits,
                                             int capS, int nbuckets) {
    __shared__ int hist[NBMAX];
    __shared__ int cur[NBMAX];
    int t = threadIdx.x;
    for (int i = t; i < nbuckets; i += 256) hist[i] = 0;
    __syncthreads();
    int e0 = blockIdx.x * EPW;
    int e1 = e0 + EPW < E ? e0 + EPW : E;
    uint32 lmask = (1u << shift) - 1u;
    for (int e = e0 + t; e < e1; e += 256) {
        int u = ei[e], v = ei[E + e];
        atomicAdd(&hist[u >> shift], 1);
        atomicAdd(&hist[v >> shift], 1);
    }
    __syncthreads();
    for (int i = t; i < nbuckets; i += 256)
        cur[i] = hist[i] > 0 ? (i * capS + atomicAdd(&bcur[i * 16], hist[i])) : 0;
    __syncthreads();
    for (int e = e0 + t; e < e1; e += 256) {
        int u = ei[e], v = ei[E + e];
        int s1 = atomicAdd(&cur[v >> shift], 1);
        stage[s1] = (((uint32)v & lmask) << sbits) | (uint32)u;
        int s2 = atomicAdd(&cur[u >> shift], 1);
        stage[s2] = (((uint32)u & lmask) << sbits) | (uint32)v;
    }
}

// ---------------- per-bucket: degree+1 scan -> offsets/oend/dinv, self first, place,
//                  then fused L2-normalize of this bucket's embedding rows -> xnw ----------------
__global__ __launch_bounds__(256) void k_bucket(const uint32* __restrict__ stage,
                                                const int* __restrict__ bcur,
                                                int* __restrict__ offsets,
                                                int* __restrict__ oend,
                                                int* __restrict__ adj,
                                                float* __restrict__ dinv,
                                                const float* __restrict__ emb,
                                                bfraw* __restrict__ xnw,
                                                int n, int shift, int sbits,
                                                int capS, int capA) {
    __shared__ int   deg[2048];
    __shared__ int   scan[256];
    __shared__ float sdinv[2048];
    int t = threadIdx.x;
    int span  = 1 << shift;
    int node0 = blockIdx.x << shift;
    int cnt = n - node0 < span ? n - node0 : span;
    uint32 smask = (1u << sbits) - 1u;
    for (int i = t; i < cnt; i += 256) deg[i] = 0;
    __syncthreads();
    int jbeg = blockIdx.x * capS;
    int jend = jbeg + bcur[blockIdx.x * 16];
    for (int j = jbeg + t; j < jend; j += 256)
        atomicAdd(&deg[stage[j] >> sbits], 1);
    __syncthreads();
    int per  = span >> 8;
    if (per < 1) per = 1;
    int base = t * per;
    int s = 0;
    for (int k = 0; k < per; k++) { int i = base + k; if (i < cnt) s += deg[i] + 1; }
    scan[t] = s;
    __syncthreads();
    for (int off = 1; off < 256; off <<= 1) {
        int v = (t >= off) ? scan[t - off] : 0;
        __syncthreads();
        scan[t] += v;
        __syncthreads();
    }
    int run = blockIdx.x * capA + scan[t] - s;
    for (int k = 0; k < per; k++) {
        int i = base + k;
        if (i < cnt) {
            int d = deg[i];
            float dd = rsqrtf(1.0f + (float)d);
            offsets[node0 + i] = run;
            oend[node0 + i]    = run + 1 + d;
            dinv[node0 + i]    = dd;
            sdinv[i]           = dd;
            adj[run] = node0 + i;      // self loop first
            deg[i] = run + 1;
            run += d + 1;
        }
    }
    __syncthreads();
    for (int j = jbeg + t; j < jend; j += 256) {
        uint32 r = stage[j];
        int slot = atomicAdd(&deg[r >> sbits], 1);
        adj[slot] = (int)(r & smask);
    }
    // fused normalize: wave per row over this bucket's nodes (sdinv visible via barrier above)
    int wv = t >> 6, lane = t & 63;
    for (int i = wv; i < cnt; i += 4) {
        float v = emb[(size_t)(node0 + i) * DIM + lane];
        float ss = v * v;
        #pragma unroll
        for (int off = 32; off; off >>= 1) ss += __shfl_xor(ss, off);
        float scale = 1.0f / fmaxf(sqrtf(ss), 1e-12f);
        xnw[(size_t)(node0 + i) * DIM + lane] = f2bf(v * scale * sdinv[i]);
    }
}

// ---------------- CSR gather: 8 lanes per row (uint4), 8 rows per load; bf16 output ----------------
#define ACC8(p) { a0 += bflo(p.x); a1 += bfhi(p.x); a2 += bflo(p.y); a3 += bfhi(p.y); \
                  a4 += bflo(p.z); a5 += bfhi(p.z); a6 += bflo(p.w); a7 += bfhi(p.w); }

__global__ void k_gather(const int* __restrict__ adj, const int* __restrict__ offsets,
                         const int* __restrict__ oend,
                         const float* __restrict__ dinv,
                         const bfraw* __restrict__ srcw,
                         bfraw* __restrict__ dstb, int n) {
    int w    = (blockIdx.x * blockDim.x + threadIdx.x) >> 6;  // wave per node
    int lane = threadIdx.x & 63;
    if (w >= n) return;
    int oct = lane >> 3;
    int ol  = lane & 7;
    int beg = offsets[w], end = oend[w];
    float dd = dinv[w];
    const uint4* rows = (const uint4*)srcw;
    float a0 = 0.f, a1 = 0.f, a2 = 0.f, a3 = 0.f;
    float a4 = 0.f, a5 = 0.f, a6 = 0.f, a7 = 0.f;
    int j = beg;
    for (; j + 32 <= end; j += 32) {
        int s0 = adj[j + oct];
        int s1 = adj[j + 8 + oct];
        int s2 = adj[j + 16 + oct];
        int s3 = adj[j + 24 + oct];
        uint4 p0 = rows[(size_t)s0 * 8 + ol];
        uint4 p1 = rows[(size_t)s1 * 8 + ol];
        uint4 p2 = rows[(size_t)s2 * 8 + ol];
        uint4 p3 = rows[(size_t)s3 * 8 + ol];
        ACC8(p0) ACC8(p1) ACC8(p2) ACC8(p3)
    }
    if (j + 16 <= end) {
        int s0 = adj[j + oct];
        int s1 = adj[j + 8 + oct];
        uint4 p0 = rows[(size_t)s0 * 8 + ol];
        uint4 p1 = rows[(size_t)s1 * 8 + ol];
        ACC8(p0) ACC8(p1)
        j += 16;
    }
    if (j + 8 <= end) {
        int s0 = adj[j + oct];
        uint4 p0 = rows[(size_t)s0 * 8 + ol];
        ACC8(p0)
        j += 8;
    }
    int rem = end - j;
    if (oct < rem) {
        int s0 = adj[j + oct];
        uint4 p0 = rows[(size_t)s0 * 8 + ol];
        ACC8(p0)
    }
    a0 += __shfl_xor(a0, 8); a0 += __shfl_xor(a0, 16); a0 += __shfl_xor(a0, 32);
    a1 += __shfl_xor(a1, 8); a1 += __shfl_xor(a1, 16); a1 += __shfl_xor(a1, 32);
    a2 += __shfl_xor(a2, 8); a2 += __shfl_xor(a2, 16); a2 += __shfl_xor(a2, 32);
    a3 += __shfl_xor(a3, 8); a3 += __shfl_xor(a3, 16); a3 += __shfl_xor(a3, 32);
    a4 += __shfl_xor(a4, 8); a4 += __shfl_xor(a4, 16); a4 += __shfl_xor(a4, 32);
    a5 += __shfl_xor(a5, 8); a5 += __shfl_xor(a5, 16); a5 += __shfl_xor(a5, 32);
    a6 += __shfl_xor(a6, 8); a6 += __shfl_xor(a6, 16); a6 += __shfl_xor(a6, 32);
    a7 += __shfl_xor(a7, 8); a7 += __shfl_xor(a7, 16); a7 += __shfl_xor(a7, 32);
    if (lane < 8) {
        uint4 o;
        o.x = pack2(dd * a0, dd * a1);
        o.y = pack2(dd * a2, dd * a3);
        o.z = pack2(dd * a4, dd * a5);
        o.w = pack2(dd * a6, dd * a7);
        ((uint4*)(dstb + (size_t)w * DIM))[ol] = o;
    }
}

// ---------------- register-tiled linear: x1w = bf16(dinv * lrelu(aggb @ W^T + b)) ----------------
__global__ __launch_bounds__(256) void k_linear_rt(
    const bfraw* __restrict__ inb, const float* __restrict__ W,
    const float* __restrict__ b, const float* __restrict__ dinv,
    bfraw* __restrict__ outw, int n)
{
    __shared__ float  sIn[64][65];
    __shared__ uint32 sWp[64][32];
    int tid = threadIdx.x;
    int r0  = blockIdx.x * 64;
    #pragma unroll
    for (int i = 0; i < 8; i++) {
        int idx = tid + i * 256;
        int k = idx & 63, cp = idx >> 6;
        sWp[k][cp] = (uint32)f2bf(W[(2 * cp) * DIM + k]) |
                     ((uint32)f2bf(W[(2 * cp + 1) * DIM + k]) << 16);
    }
    int limu = ((n - r0 < 64 ? n - r0 : 64) * DIM) >> 1;
    const uint32* inu = (const uint32*)(inb + (size_t)r0 * DIM);
    for (int idx = tid; idx < limu; idx += 256) {
        uint32 u = inu[idx];
        int r = idx >> 5, c = (idx & 31) * 2;
        sIn[r][c] = bflo(u); sIn[r][c + 1] = bfhi(u);
    }
    __syncthreads();

    int ri = (tid >> 4) << 2;
    int ci = (tid & 15) << 2;
    int cp = ci >> 1;
    float acc[4][4];
    #pragma unroll
    for (int j = 0; j < 4; j++) {
        float bj = b[ci + j];
        #pragma unroll
        for (int i = 0; i < 4; i++) acc[i][j] = bj;
    }
    #pragma unroll 2
    for (int k4 = 0; k4 < 16; k4++) {
        int k = k4 * 4;
        float4 A0 = *(const float4*)&sIn[ri + 0][k];
        float4 A1 = *(const float4*)&sIn[ri + 1][k];
        float4 A2 = *(const float4*)&sIn[ri + 2][k];
        float4 A3 = *(const float4*)&sIn[ri + 3][k];
        #pragma unroll
        for (int kk = 0; kk < 4; kk++) {
            uint2 uw = *(const uint2*)&sWp[k + kk][cp];
            float w0 = bflo(uw.x), w1 = bfhi(uw.x);
            float w2 = bflo(uw.y), w3 = bfhi(uw.y);
            float a0 = kk == 0 ? A0.x : kk == 1 ? A0.y : kk == 2 ? A0.z : A0.w;
            float a1 = kk == 0 ? A1.x : kk == 1 ? A1.y : kk == 2 ? A1.z : A1.w;
            float a2 = kk == 0 ? A2.x : kk == 1 ? A2.y : kk == 2 ? A2.z : A2.w;
            float a3 = kk == 0 ? A3.x : kk == 1 ? A3.y : kk == 2 ? A3.z : A3.w;
            acc[0][0] = fmaf(a0, w0, acc[0][0]); acc[0][1] = fmaf(a0, w1, acc[0][1]);
            acc[0][2] = fmaf(a0, w2, acc[0][2]); acc[0][3] = fmaf(a0, w3, acc[0][3]);
            acc[1][0] = fmaf(a1, w0, acc[1][0]); acc[1][1] = fmaf(a1, w1, acc[1][1]);
            acc[1][2] = fmaf(a1, w2, acc[1][2]); acc[1][3] = fmaf(a1, w3, acc[1][3]);
            acc[2][0] = fmaf(a2, w0, acc[2][0]); acc[2][1] = fmaf(a2, w1, acc[2][1]);
            acc[2][2] = fmaf(a2, w2, acc[2][2]); acc[2][3] = fmaf(a2, w3, acc[2][3]);
            acc[3][0] = fmaf(a3, w0, acc[3][0]); acc[3][1] = fmaf(a3, w1, acc[3][1]);
            acc[3][2] = fmaf(a3, w2, acc[3][2]); acc[3][3] = fmaf(a3, w3, acc[3][3]);
        }
    }
    #pragma unroll
    for (int i = 0; i < 4; i++) {
        int r = r0 + ri + i;
        if (r >= n) break;
        float dd = dinv[r];
        float e0 = acc[i][0] > 0.f ? acc[i][0] : NEG_SLOPE * acc[i][0];
        float e1 = acc[i][1] > 0.f ? acc[i][1] : NEG_SLOPE * acc[i][1];
        float e2 = acc[i][2] > 0.f ? acc[i][2] : NEG_SLOPE * acc[i][2];
        float e3 = acc[i][3] > 0.f ? acc[i][3] : NEG_SLOPE * acc[i][3];
        ushort4 ow;
        ow.x = f2bf(e0 * dd); ow.y = f2bf(e1 * dd);
        ow.z = f2bf(e2 * dd); ow.w = f2bf(e3 * dd);
        *(ushort4*)&outw[(size_t)r * DIM + ci] = ow;
    }
}

// ---------------- final: out = (xnw + x1w)/dinv + lrelu(aggb@W2^T+b2) + (aggb@W3^T+b3) ----------------
__global__ __launch_bounds__(256) void k_final_rt(
    const bfraw* __restrict__ aggb, const bfraw* __restrict__ xnw,
    const bfraw* __restrict__ x1w, const float* __restrict__ dinv,
    const float* __restrict__ W2, const float* __restrict__ b2,
    const float* __restrict__ W3, const float* __restrict__ b3,
    float* __restrict__ out, int n)
{
    __shared__ float  sIn[64][65];
    __shared__ uint32 sW2p[64][32];
    __shared__ uint32 sW3p[64][32];
    int tid = threadIdx.x;
    int r0  = blockIdx.x * 64;
    #pragma unroll
    for (int i = 0; i < 8; i++) {
        int idx = tid + i * 256;
        int k = idx & 63, cp = idx >> 6;
        sW2p[k][cp] = (uint32)f2bf(W2[(2 * cp) * DIM + k]) |
                      ((uint32)f2bf(W2[(2 * cp + 1) * DIM + k]) << 16);
        sW3p[k][cp] = (uint32)f2bf(W3[(2 * cp) * DIM + k]) |
                      ((uint32)f2bf(W3[(2 * cp + 1) * DIM + k]) << 16);
    }
    int limu = ((n - r0 < 64 ? n - r0 : 64) * DIM) >> 1;
    const uint32* inu = (const uint32*)(aggb + (size_t)r0 * DIM);
    for (int idx = tid; idx < limu; idx += 256) {
        uint32 u = inu[idx];
        int r = idx >> 5, c = (idx & 31) * 2;
        sIn[r][c] = bflo(u); sIn[r][c + 1] = bfhi(u);
    }
    __syncthreads();

    int ri = (tid >> 4) << 2;
    int ci = (tid & 15) << 2;
    int cp = ci >> 1;
    float acc2[4][4], acc3[4][4];
    #pragma unroll
    for (int j = 0; j < 4; j++) {
        float bj2 = b2[ci + j], bj3 = b3[ci + j];
        #pragma unroll
        for (int i = 0; i < 4; i++) { acc2[i][j] = bj2; acc3[i][j] = bj3; }
    }
    #pragma unroll 2
    for (int k4 = 0; k4 < 16; k4++) {
        int k = k4 * 4;
        float4 A0 = *(const float4*)&sIn[ri + 0][k];
        float4 A1 = *(const float4*)&sIn[ri + 1][k];
        float4 A2 = *(const float4*)&sIn[ri + 2][k];
        float4 A3 = *(const float4*)&sIn[ri + 3][k];
        #pragma unroll
        for (int kk = 0; kk < 4; kk++) {
            uint2 u2 = *(const uint2*)&sW2p[k + kk][cp];
            uint2 u3 = *(const uint2*)&sW3p[k + kk][cp];
            float a0 = kk == 0 ? A0.x : kk == 1 ? A0.y : kk == 2 ? A0.z : A0.w;
            float a1 = kk == 0 ? A1.x : kk == 1 ? A1.y : kk == 2 ? A1.z : A1.w;
            float a2 = kk == 0 ? A2.x : kk == 1 ? A2.y : kk == 2 ? A2.z : A2.w;
            float a3 = kk == 0 ? A3.x : kk == 1 ? A3.y : kk == 2 ? A3.z : A3.w;
            float u0 = bflo(u2.x), u1 = bfhi(u2.x), u2c = bflo(u2.y), u3c = bfhi(u2.y);
            float v0 = bflo(u3.x), v1 = bfhi(u3.x), v2c = bflo(u3.y), v3c = bfhi(u3.y);
            acc2[0][0] = fmaf(a0, u0, acc2[0][0]); acc2[0][1] = fmaf(a0, u1, acc2[0][1]);
            acc2[0][2] = fmaf(a0, u2c, acc2[0][2]); acc2[0][3] = fmaf(a0, u3c, acc2[0][3]);
            acc2[1][0] = fmaf(a1, u0, acc2[1][0]); acc2[1][1] = fmaf(a1, u1, acc2[1][1]);
            acc2[1][2] = fmaf(a1, u2c, acc2[1][2]); acc2[1][3] = fmaf(a1, u3c, acc2[1][3]);
            acc2[2][0] = fmaf(a2, u0, acc2[2][0]); acc2[2][1] = fmaf(a2, u1, acc2[2][1]);
            acc2[2][2] = fmaf(a2, u2c, acc2[2][2]); acc2[2][3] = fmaf(a2, u3c, acc2[2][3]);
            acc2[3][0] = fmaf(a3, u0, acc2[3][0]); acc2[3][1] = fmaf(a3, u1, acc2[3][1]);
            acc2[3][2] = fmaf(a3, u2c, acc2[3][2]); acc2[3][3] = fmaf(a3, u3c, acc2[3][3]);
            acc3[0][0] = fmaf(a0, v0, acc3[0][0]); acc3[0][1] = fmaf(a0, v1, acc3[0][1]);
            acc3[0][2] = fmaf(a0, v2c, acc3[0][2]); acc3[0][3] = fmaf(a0, v3c, acc3[0][3]);
            acc3[1][0] = fmaf(a1, v0, acc3[1][0]); acc3[1][1] = fmaf(a1, v1, acc3[1][1]);
            acc3[1][2] = fmaf(a1, v2c, acc3[1][2]); acc3[1][3] = fmaf(a1, v3c, acc3[1][3]);
            acc3[2][0] = fmaf(a2, v0, acc3[2][0]); acc3[2][1] = fmaf(a2, v1, acc3[2][1]);
            acc3[2][2] = fmaf(a2, v2c, acc3[2][2]); acc3[2][3] = fmaf(a2, v3c, acc3[2][3]);
            acc3[3][0] = fmaf(a3, v0, acc3[3][0]); acc3[3][1] = fmaf(a3, v1, acc3[3][1]);
            acc3[3][2] = fmaf(a3, v2c, acc3[3][2]); acc3[3][3] = fmaf(a3, v3c, acc3[3][3]);
        }
    }
    #pragma unroll
    for (int i = 0; i < 4; i++) {
        int r = r0 + ri + i;
        if (r >= n) break;
        size_t base = (size_t)r * DIM + ci;
        float rdd = 1.0f / dinv[r];
        uint2 uxn = *(const uint2*)&xnw[base];
        uint2 ux1 = *(const uint2*)&x1w[base];
        float4 o;
        float e0 = acc2[i][0] > 0.f ? acc2[i][0] : NEG_SLOPE * acc2[i][0];
        float e1 = acc2[i][1] > 0.f ? acc2[i][1] : NEG_SLOPE * acc2[i][1];
        float e2 = acc2[i][2] > 0.f ? acc2[i][2] : NEG_SLOPE * acc2[i][2];
        float e3 = acc2[i][3] > 0.f ? acc2[i][3] : NEG_SLOPE * acc2[i][3];
        o.x = (bflo(uxn.x) + bflo(ux1.x)) * rdd + e0 + acc3[i][0];
        o.y = (bfhi(uxn.x) + bfhi(ux1.x)) * rdd + e1 + acc3[i][1];
        o.z = (bflo(uxn.y) + bflo(ux1.y)) * rdd + e2 + acc3[i][2];
        o.w = (bfhi(uxn.y) + bfhi(ux1.y)) * rdd + e3 + acc3[i][3];
        *(float4*)&out[base] = o;
    }
}

// ---------------- launcher ----------------

extern "C" void kernel_launch(void* const* d_in, const int* in_sizes, int n_in,
                              void* d_out, int out_size, void* d_ws, size_t ws_size,
                              hipStream_t stream) {
    const int*   ei  = (const int*)d_in[0];
    const float* emb = (const float*)d_in[1];
    const float* W1  = (const float*)d_in[2];
    const float* b1  = (const float*)d_in[3];
    const float* W2  = (const float*)d_in[4];
    const float* b2  = (const float*)d_in[5];
    const float* W3  = (const float*)d_in[6];
    const float* b3  = (const float*)d_in[7];
    float* out = (float*)d_out;

    int E = in_sizes[0] / 2;
    int n = in_sizes[1] / DIM;
    size_t nD = (size_t)n * DIM;

    // bucket shift: 256-node buckets; <=NBMAX buckets (n<=262144 at shift=8)
    int shift = 8;
    while ((((size_t)n + ((size_t)1 << shift) - 1) >> shift) > NBMAX) shift++;
    int nbuckets = (int)(((size_t)n + ((size_t)1 << shift) - 1) >> shift);
    int sbits = 32 - shift;
    int span  = 1 << shift;

    // fixed-capacity bucket regions: mean + 25% + 2048 (>>sigma for random edges)
    int capS = (int)(2 * (size_t)E / nbuckets + (2 * (size_t)E) / (4 * (size_t)nbuckets) + 2048);
    int capA = capS + span;

    // workspace layout -- bulk arrays 128B-aligned; stage has its OWN region
    // (k_bucket now writes xnw while other blocks read stage -> no aliasing allowed)
    size_t np   = ((size_t)n + 1023) & ~1023ull;
    size_t adjn = ((size_t)nbuckets * capA + 31) & ~31ull;
    int*   bcur    = (int*)d_ws;              // NBMAX*16 ints (zeroed each call)
    int*   offsets = bcur + NBMAX * 16;       // np
    int*   oendA   = offsets + np;            // np
    float* dinv    = (float*)(oendA + np);    // np
    bfraw* aggb    = (bfraw*)(dinv + np);     // nD bf16
    bfraw* xnw     = aggb + nD;               // nD bf16 (128B aligned)
    bfraw* x1w     = xnw + nD;                // nD bf16
    int*   adj     = (int*)(x1w + nD);        // nbuckets*capA ints (gapped)
    uint32* stage  = (uint32*)(adj + adjn);   // nbuckets*capS uints (separate region)

    const int B = 256;

    // --- CSR build + fused normalize ---
    hipMemsetAsync(bcur, 0, NBMAX * 16 * sizeof(int), stream);
    k_bin   <<<(E + EPW - 1) / EPW, B, 0, stream>>>(ei, E, stage, bcur, shift, sbits,
                                                    capS, nbuckets);
    k_bucket<<<nbuckets, B, 0, stream>>>(stage, bcur, offsets, oendA, adj, dinv,
                                         emb, xnw, n, shift, sbits, capS, capA);

    // --- layer 1 ---
    k_gather   <<<(n + 3) / 4, B, 0, stream>>>(adj, offsets, oendA, dinv, xnw, aggb, n);
    k_linear_rt<<<(n + 63) / 64, B, 0, stream>>>(aggb, W1, b1, dinv, x1w, n);

    // --- layers 2+3 fused ---
    k_gather   <<<(n + 3) / 4, B, 0, stream>>>(adj, offsets, oendA, dinv, x1w, aggb, n);
    k_final_rt <<<(n + 63) / 64, B, 0, stream>>>(aggb, xnw, x1w, dinv, W2, b2, W3, b3, out, n);
}

// Round 19
// 211.135 us; speedup vs baseline: 1.1011x; 1.1011x over previous
//
#include <hip/hip_runtime.h>
#include <math.h>

#define DIM 64
#define NEG_SLOPE 0.01f
#define NBMAX 1024

typedef unsigned short bfraw;
typedef unsigned int uint32;

__device__ __forceinline__ bfraw f2bf(float f) {
    unsigned int u = __float_as_uint(f);
    unsigned int r = (u + 0x7FFFu + ((u >> 16) & 1u)) >> 16;  // RNE
    return (bfraw)r;
}
__device__ __forceinline__ float bflo(uint32 u) { return __uint_as_float(u << 16); }
__device__ __forceinline__ float bfhi(uint32 u) { return __uint_as_float(u & 0xFFFF0000u); }
__device__ __forceinline__ uint32 pack2(float lo, float hi) {
    return (uint32)f2bf(lo) | ((uint32)f2bf(hi) << 16);
}

// ---------------- bin packed records ((local_dst<<sbits)|src) into fixed-cap bucket regions ----------------
// bcur zeroed by hipMemsetAsync; cursors bucket-relative, +b*capS at use.
#define EPW 4096

__global__ __launch_bounds__(256) void k_bin(const int* __restrict__ ei, int E,
                                             uint32* __restrict__ stage,
                                             int* __restrict__ bcur, int shift, int sbits,
                                             int capS, int nbuckets) {
    __shared__ int hist[NBMAX];
    __shared__ int cur[NBMAX];
    int t = threadIdx.x;
    for (int i = t; i < nbuckets; i += 256) hist[i] = 0;
    __syncthreads();
    int e0 = blockIdx.x * EPW;
    int e1 = e0 + EPW < E ? e0 + EPW : E;
    uint32 lmask = (1u << shift) - 1u;
    for (int e = e0 + t; e < e1; e += 256) {
        int u = ei[e], v = ei[E + e];
        atomicAdd(&hist[u >> shift], 1);
        atomicAdd(&hist[v >> shift], 1);
    }
    __syncthreads();
    for (int i = t; i < nbuckets; i += 256)
        cur[i] = hist[i] > 0 ? (i * capS + atomicAdd(&bcur[i * 16], hist[i])) : 0;
    __syncthreads();
    for (int e = e0 + t; e < e1; e += 256) {
        int u = ei[e], v = ei[E + e];
        int s1 = atomicAdd(&cur[v >> shift], 1);
        stage[s1] = (((uint32)v & lmask) << sbits) | (uint32)u;
        int s2 = atomicAdd(&cur[u >> shift], 1);
        stage[s2] = (((uint32)u & lmask) << sbits) | (uint32)v;
    }
}

// ---------------- per-bucket: degree+1 scan -> offsets/oend/dinv, self first, then place ----------------
__global__ __launch_bounds__(256) void k_bucket(const uint32* __restrict__ stage,
                                                const int* __restrict__ bcur,
                                                int* __restrict__ offsets,
                                                int* __restrict__ oend,
                                                int* __restrict__ adj,
                                                float* __restrict__ dinv,
                                                int n, int shift, int sbits,
                                                int capS, int capA) {
    __shared__ int deg[2048];
    __shared__ int scan[256];
    int t = threadIdx.x;
    int span  = 1 << shift;
    int node0 = blockIdx.x << shift;
    int cnt = n - node0 < span ? n - node0 : span;
    uint32 smask = (1u << sbits) - 1u;
    for (int i = t; i < cnt; i += 256) deg[i] = 0;
    __syncthreads();
    int jbeg = blockIdx.x * capS;
    int jend = jbeg + bcur[blockIdx.x * 16];
    for (int j = jbeg + t; j < jend; j += 256)
        atomicAdd(&deg[stage[j] >> sbits], 1);
    __syncthreads();
    int per  = span >> 8;       // span=256 -> per=1
    if (per < 1) per = 1;
    int base = t * per;
    int s = 0;
    for (int k = 0; k < per; k++) { int i = base + k; if (i < cnt) s += deg[i] + 1; }
    scan[t] = s;
    __syncthreads();
    for (int off = 1; off < 256; off <<= 1) {
        int v = (t >= off) ? scan[t - off] : 0;
        __syncthreads();
        scan[t] += v;
        __syncthreads();
    }
    int run = blockIdx.x * capA + scan[t] - s;
    for (int k = 0; k < per; k++) {
        int i = base + k;
        if (i < cnt) {
            int d = deg[i];
            offsets[node0 + i] = run;
            oend[node0 + i]    = run + 1 + d;
            dinv[node0 + i] = rsqrtf(1.0f + (float)d);
            adj[run] = node0 + i;      // self loop first
            deg[i] = run + 1;
            run += d + 1;
        }
    }
    __syncthreads();
    for (int j = jbeg + t; j < jend; j += 256) {
        uint32 r = stage[j];
        int slot = atomicAdd(&deg[r >> sbits], 1);
        adj[slot] = (int)(r & smask);
    }
}

// ---------------- row L2-normalize -> bf16 prescaled (xnw) only ----------------
__global__ void k_normalize(const float* __restrict__ x, const float* __restrict__ dinv,
                            bfraw* __restrict__ xnw, int n) {
    int row  = (blockIdx.x * blockDim.x + threadIdx.x) >> 6;
    int lane = threadIdx.x & 63;
    if (row >= n) return;
    float v = x[row * DIM + lane];
    float s = v * v;
    #pragma unroll
    for (int off = 32; off; off >>= 1) s += __shfl_xor(s, off);
    float scale = 1.0f / fmaxf(sqrtf(s), 1e-12f);
    xnw[row * DIM + lane] = f2bf(v * scale * dinv[row]);
}

// ---------------- CSR gather: 8 lanes per row (uint4), 8 rows per load; bf16 output ----------------
#define ACC8(p) { a0 += bflo(p.x); a1 += bfhi(p.x); a2 += bflo(p.y); a3 += bfhi(p.y); \
                  a4 += bflo(p.z); a5 += bfhi(p.z); a6 += bflo(p.w); a7 += bfhi(p.w); }

__global__ void k_gather(const int* __restrict__ adj, const int* __restrict__ offsets,
                         const int* __restrict__ oend,
                         const float* __restrict__ dinv,
                         const bfraw* __restrict__ srcw,
                         bfraw* __restrict__ dstb, int n) {
    int w    = (blockIdx.x * blockDim.x + threadIdx.x) >> 6;  // wave per node
    int lane = threadIdx.x & 63;
    if (w >= n) return;
    int oct = lane >> 3;
    int ol  = lane & 7;
    int beg = offsets[w], end = oend[w];
    float dd = dinv[w];
    const uint4* rows = (const uint4*)srcw;
    float a0 = 0.f, a1 = 0.f, a2 = 0.f, a3 = 0.f;
    float a4 = 0.f, a5 = 0.f, a6 = 0.f, a7 = 0.f;
    int j = beg;
    for (; j + 32 <= end; j += 32) {
        int s0 = adj[j + oct];
        int s1 = adj[j + 8 + oct];
        int s2 = adj[j + 16 + oct];
        int s3 = adj[j + 24 + oct];
        uint4 p0 = rows[(size_t)s0 * 8 + ol];
        uint4 p1 = rows[(size_t)s1 * 8 + ol];
        uint4 p2 = rows[(size_t)s2 * 8 + ol];
        uint4 p3 = rows[(size_t)s3 * 8 + ol];
        ACC8(p0) ACC8(p1) ACC8(p2) ACC8(p3)
    }
    if (j + 16 <= end) {
        int s0 = adj[j + oct];
        int s1 = adj[j + 8 + oct];
        uint4 p0 = rows[(size_t)s0 * 8 + ol];
        uint4 p1 = rows[(size_t)s1 * 8 + ol];
        ACC8(p0) ACC8(p1)
        j += 16;
    }
    if (j + 8 <= end) {
        int s0 = adj[j + oct];
        uint4 p0 = rows[(size_t)s0 * 8 + ol];
        ACC8(p0)
        j += 8;
    }
    int rem = end - j;
    if (oct < rem) {
        int s0 = adj[j + oct];
        uint4 p0 = rows[(size_t)s0 * 8 + ol];
        ACC8(p0)
    }
    a0 += __shfl_xor(a0, 8); a0 += __shfl_xor(a0, 16); a0 += __shfl_xor(a0, 32);
    a1 += __shfl_xor(a1, 8); a1 += __shfl_xor(a1, 16); a1 += __shfl_xor(a1, 32);
    a2 += __shfl_xor(a2, 8); a2 += __shfl_xor(a2, 16); a2 += __shfl_xor(a2, 32);
    a3 += __shfl_xor(a3, 8); a3 += __shfl_xor(a3, 16); a3 += __shfl_xor(a3, 32);
    a4 += __shfl_xor(a4, 8); a4 += __shfl_xor(a4, 16); a4 += __shfl_xor(a4, 32);
    a5 += __shfl_xor(a5, 8); a5 += __shfl_xor(a5, 16); a5 += __shfl_xor(a5, 32);
    a6 += __shfl_xor(a6, 8); a6 += __shfl_xor(a6, 16); a6 += __shfl_xor(a6, 32);
    a7 += __shfl_xor(a7, 8); a7 += __shfl_xor(a7, 16); a7 += __shfl_xor(a7, 32);
    if (lane < 8) {
        uint4 o;
        o.x = pack2(dd * a0, dd * a1);
        o.y = pack2(dd * a2, dd * a3);
        o.z = pack2(dd * a4, dd * a5);
        o.w = pack2(dd * a6, dd * a7);
        ((uint4*)(dstb + (size_t)w * DIM))[ol] = o;
    }
}

// ---------------- register-tiled linear: x1w = bf16(dinv * lrelu(aggb @ W^T + b)) ----------------
__global__ __launch_bounds__(256) void k_linear_rt(
    const bfraw* __restrict__ inb, const float* __restrict__ W,
    const float* __restrict__ b, const float* __restrict__ dinv,
    bfraw* __restrict__ outw, int n)
{
    __shared__ float  sIn[64][65];
    __shared__ uint32 sWp[64][32];
    int tid = threadIdx.x;
    int r0  = blockIdx.x * 64;
    #pragma unroll
    for (int i = 0; i < 8; i++) {
        int idx = tid + i * 256;
        int k = idx & 63, cp = idx >> 6;
        sWp[k][cp] = (uint32)f2bf(W[(2 * cp) * DIM + k]) |
                     ((uint32)f2bf(W[(2 * cp + 1) * DIM + k]) << 16);
    }
    int limu = ((n - r0 < 64 ? n - r0 : 64) * DIM) >> 1;
    const uint32* inu = (const uint32*)(inb + (size_t)r0 * DIM);
    for (int idx = tid; idx < limu; idx += 256) {
        uint32 u = inu[idx];
        int r = idx >> 5, c = (idx & 31) * 2;
        sIn[r][c] = bflo(u); sIn[r][c + 1] = bfhi(u);
    }
    __syncthreads();

    int ri = (tid >> 4) << 2;
    int ci = (tid & 15) << 2;
    int cp = ci >> 1;
    float acc[4][4];
    #pragma unroll
    for (int j = 0; j < 4; j++) {
        float bj = b[ci + j];
        #pragma unroll
        for (int i = 0; i < 4; i++) acc[i][j] = bj;
    }
    #pragma unroll 2
    for (int k4 = 0; k4 < 16; k4++) {
        int k = k4 * 4;
        float4 A0 = *(const float4*)&sIn[ri + 0][k];
        float4 A1 = *(const float4*)&sIn[ri + 1][k];
        float4 A2 = *(const float4*)&sIn[ri + 2][k];
        float4 A3 = *(const float4*)&sIn[ri + 3][k];
        #pragma unroll
        for (int kk = 0; kk < 4; kk++) {
            uint2 uw = *(const uint2*)&sWp[k + kk][cp];
            float w0 = bflo(uw.x), w1 = bfhi(uw.x);
            float w2 = bflo(uw.y), w3 = bfhi(uw.y);
            float a0 = kk == 0 ? A0.x : kk == 1 ? A0.y : kk == 2 ? A0.z : A0.w;
            float a1 = kk == 0 ? A1.x : kk == 1 ? A1.y : kk == 2 ? A1.z : A1.w;
            float a2 = kk == 0 ? A2.x : kk == 1 ? A2.y : kk == 2 ? A2.z : A2.w;
            float a3 = kk == 0 ? A3.x : kk == 1 ? A3.y : kk == 2 ? A3.z : A3.w;
            acc[0][0] = fmaf(a0, w0, acc[0][0]); acc[0][1] = fmaf(a0, w1, acc[0][1]);
            acc[0][2] = fmaf(a0, w2, acc[0][2]); acc[0][3] = fmaf(a0, w3, acc[0][3]);
            acc[1][0] = fmaf(a1, w0, acc[1][0]); acc[1][1] = fmaf(a1, w1, acc[1][1]);
            acc[1][2] = fmaf(a1, w2, acc[1][2]); acc[1][3] = fmaf(a1, w3, acc[1][3]);
            acc[2][0] = fmaf(a2, w0, acc[2][0]); acc[2][1] = fmaf(a2, w1, acc[2][1]);
            acc[2][2] = fmaf(a2, w2, acc[2][2]); acc[2][3] = fmaf(a2, w3, acc[2][3]);
            acc[3][0] = fmaf(a3, w0, acc[3][0]); acc[3][1] = fmaf(a3, w1, acc[3][1]);
            acc[3][2] = fmaf(a3, w2, acc[3][2]); acc[3][3] = fmaf(a3, w3, acc[3][3]);
        }
    }
    #pragma unroll
    for (int i = 0; i < 4; i++) {
        int r = r0 + ri + i;
        if (r >= n) break;
        float dd = dinv[r];
        float e0 = acc[i][0] > 0.f ? acc[i][0] : NEG_SLOPE * acc[i][0];
        float e1 = acc[i][1] > 0.f ? acc[i][1] : NEG_SLOPE * acc[i][1];
        float e2 = acc[i][2] > 0.f ? acc[i][2] : NEG_SLOPE * acc[i][2];
        float e3 = acc[i][3] > 0.f ? acc[i][3] : NEG_SLOPE * acc[i][3];
        ushort4 ow;
        ow.x = f2bf(e0 * dd); ow.y = f2bf(e1 * dd);
        ow.z = f2bf(e2 * dd); ow.w = f2bf(e3 * dd);
        *(ushort4*)&outw[(size_t)r * DIM + ci] = ow;
    }
}

// ---------------- final: out = (xnw + x1w)/dinv + lrelu(aggb@W2^T+b2) + (aggb@W3^T+b3) ----------------
__global__ __launch_bounds__(256) void k_final_rt(
    const bfraw* __restrict__ aggb, const bfraw* __restrict__ xnw,
    const bfraw* __restrict__ x1w, const float* __restrict__ dinv,
    const float* __restrict__ W2, const float* __restrict__ b2,
    const float* __restrict__ W3, const float* __restrict__ b3,
    float* __restrict__ out, int n)
{
    __shared__ float  sIn[64][65];
    __shared__ uint32 sW2p[64][32];
    __shared__ uint32 sW3p[64][32];
    int tid = threadIdx.x;
    int r0  = blockIdx.x * 64;
    #pragma unroll
    for (int i = 0; i < 8; i++) {
        int idx = tid + i * 256;
        int k = idx & 63, cp = idx >> 6;
        sW2p[k][cp] = (uint32)f2bf(W2[(2 * cp) * DIM + k]) |
                      ((uint32)f2bf(W2[(2 * cp + 1) * DIM + k]) << 16);
        sW3p[k][cp] = (uint32)f2bf(W3[(2 * cp) * DIM + k]) |
                      ((uint32)f2bf(W3[(2 * cp + 1) * DIM + k]) << 16);
    }
    int limu = ((n - r0 < 64 ? n - r0 : 64) * DIM) >> 1;
    const uint32* inu = (const uint32*)(aggb + (size_t)r0 * DIM);
    for (int idx = tid; idx < limu; idx += 256) {
        uint32 u = inu[idx];
        int r = idx >> 5, c = (idx & 31) * 2;
        sIn[r][c] = bflo(u); sIn[r][c + 1] = bfhi(u);
    }
    __syncthreads();

    int ri = (tid >> 4) << 2;
    int ci = (tid & 15) << 2;
    int cp = ci >> 1;
    float acc2[4][4], acc3[4][4];
    #pragma unroll
    for (int j = 0; j < 4; j++) {
        float bj2 = b2[ci + j], bj3 = b3[ci + j];
        #pragma unroll
        for (int i = 0; i < 4; i++) { acc2[i][j] = bj2; acc3[i][j] = bj3; }
    }
    #pragma unroll 2
    for (int k4 = 0; k4 < 16; k4++) {
        int k = k4 * 4;
        float4 A0 = *(const float4*)&sIn[ri + 0][k];
        float4 A1 = *(const float4*)&sIn[ri + 1][k];
        float4 A2 = *(const float4*)&sIn[ri + 2][k];
        float4 A3 = *(const float4*)&sIn[ri + 3][k];
        #pragma unroll
        for (int kk = 0; kk < 4; kk++) {
            uint2 u2 = *(const uint2*)&sW2p[k + kk][cp];
            uint2 u3 = *(const uint2*)&sW3p[k + kk][cp];
            float a0 = kk == 0 ? A0.x : kk == 1 ? A0.y : kk == 2 ? A0.z : A0.w;
            float a1 = kk == 0 ? A1.x : kk == 1 ? A1.y : kk == 2 ? A1.z : A1.w;
            float a2 = kk == 0 ? A2.x : kk == 1 ? A2.y : kk == 2 ? A2.z : A2.w;
            float a3 = kk == 0 ? A3.x : kk == 1 ? A3.y : kk == 2 ? A3.z : A3.w;
            float u0 = bflo(u2.x), u1 = bfhi(u2.x), u2c = bflo(u2.y), u3c = bfhi(u2.y);
            float v0 = bflo(u3.x), v1 = bfhi(u3.x), v2c = bflo(u3.y), v3c = bfhi(u3.y);
            acc2[0][0] = fmaf(a0, u0, acc2[0][0]); acc2[0][1] = fmaf(a0, u1, acc2[0][1]);
            acc2[0][2] = fmaf(a0, u2c, acc2[0][2]); acc2[0][3] = fmaf(a0, u3c, acc2[0][3]);
            acc2[1][0] = fmaf(a1, u0, acc2[1][0]); acc2[1][1] = fmaf(a1, u1, acc2[1][1]);
            acc2[1][2] = fmaf(a1, u2c, acc2[1][2]); acc2[1][3] = fmaf(a1, u3c, acc2[1][3]);
            acc2[2][0] = fmaf(a2, u0, acc2[2][0]); acc2[2][1] = fmaf(a2, u1, acc2[2][1]);
            acc2[2][2] = fmaf(a2, u2c, acc2[2][2]); acc2[2][3] = fmaf(a2, u3c, acc2[2][3]);
            acc2[3][0] = fmaf(a3, u0, acc2[3][0]); acc2[3][1] = fmaf(a3, u1, acc2[3][1]);
            acc2[3][2] = fmaf(a3, u2c, acc2[3][2]); acc2[3][3] = fmaf(a3, u3c, acc2[3][3]);
            acc3[0][0] = fmaf(a0, v0, acc3[0][0]); acc3[0][1] = fmaf(a0, v1, acc3[0][1]);
            acc3[0][2] = fmaf(a0, v2c, acc3[0][2]); acc3[0][3] = fmaf(a0, v3c, acc3[0][3]);
            acc3[1][0] = fmaf(a1, v0, acc3[1][0]); acc3[1][1] = fmaf(a1, v1, acc3[1][1]);
            acc3[1][2] = fmaf(a1, v2c, acc3[1][2]); acc3[1][3] = fmaf(a1, v3c, acc3[1][3]);
            acc3[2][0] = fmaf(a2, v0, acc3[2][0]); acc3[2][1] = fmaf(a2, v1, acc3[2][1]);
            acc3[2][2] = fmaf(a2, v2c, acc3[2][2]); acc3[2][3] = fmaf(a2, v3c, acc3[2][3]);
            acc3[3][0] = fmaf(a3, v0, acc3[3][0]); acc3[3][1] = fmaf(a3, v1, acc3[3][1]);
            acc3[3][2] = fmaf(a3, v2c, acc3[3][2]); acc3[3][3] = fmaf(a3, v3c, acc3[3][3]);
        }
    }
    #pragma unroll
    for (int i = 0; i < 4; i++) {
        int r = r0 + ri + i;
        if (r >= n) break;
        size_t base = (size_t)r * DIM + ci;
        float rdd = 1.0f / dinv[r];
        uint2 uxn = *(const uint2*)&xnw[base];
        uint2 ux1 = *(const uint2*)&x1w[base];
        float4 o;
        float e0 = acc2[i][0] > 0.f ? acc2[i][0] : NEG_SLOPE * acc2[i][0];
        float e1 = acc2[i][1] > 0.f ? acc2[i][1] : NEG_SLOPE * acc2[i][1];
        float e2 = acc2[i][2] > 0.f ? acc2[i][2] : NEG_SLOPE * acc2[i][2];
        float e3 = acc2[i][3] > 0.f ? acc2[i][3] : NEG_SLOPE * acc2[i][3];
        o.x = (bflo(uxn.x) + bflo(ux1.x)) * rdd + e0 + acc3[i][0];
        o.y = (bfhi(uxn.x) + bfhi(ux1.x)) * rdd + e1 + acc3[i][1];
        o.z = (bflo(uxn.y) + bflo(ux1.y)) * rdd + e2 + acc3[i][2];
        o.w = (bfhi(uxn.y) + bfhi(ux1.y)) * rdd + e3 + acc3[i][3];
        *(float4*)&out[base] = o;
    }
}

// ---------------- launcher ----------------

extern "C" void kernel_launch(void* const* d_in, const int* in_sizes, int n_in,
                              void* d_out, int out_size, void* d_ws, size_t ws_size,
                              hipStream_t stream) {
    const int*   ei  = (const int*)d_in[0];
    const float* emb = (const float*)d_in[1];
    const float* W1  = (const float*)d_in[2];
    const float* b1  = (const float*)d_in[3];
    const float* W2  = (const float*)d_in[4];
    const float* b2  = (const float*)d_in[5];
    const float* W3  = (const float*)d_in[6];
    const float* b3  = (const float*)d_in[7];
    float* out = (float*)d_out;

    int E = in_sizes[0] / 2;
    int n = in_sizes[1] / DIM;
    size_t nD = (size_t)n * DIM;

    // bucket shift: 256-node buckets; <=NBMAX buckets (n<=262144 at shift=8)
    int shift = 8;
    while ((((size_t)n + ((size_t)1 << shift) - 1) >> shift) > NBMAX) shift++;
    int nbuckets = (int)(((size_t)n + ((size_t)1 << shift) - 1) >> shift);
    int sbits = 32 - shift;
    int span  = 1 << shift;

    // fixed-capacity bucket regions: mean + 25% + 2048 (>>sigma for random edges)
    int capS = (int)(2 * (size_t)E / nbuckets + (2 * (size_t)E) / (4 * (size_t)nbuckets) + 2048);
    if ((size_t)nbuckets * capS > nD) capS = (int)(nD / nbuckets);  // stage fits aggb+xnw alias
    int capA = capS + span;

    // workspace layout -- bulk arrays 128B-aligned; stage aliases aggb(+xnw head)
    size_t np   = ((size_t)n + 1023) & ~1023ull;
    size_t adjn = ((size_t)nbuckets * capA + 31) & ~31ull;
    int*   bcur    = (int*)d_ws;              // NBMAX*16 ints (zeroed each call)
    int*   offsets = bcur + NBMAX * 16;       // np
    int*   oendA   = offsets + np;            // np
    float* dinv    = (float*)(oendA + np);    // np
    bfraw* aggb    = (bfraw*)(dinv + np);     // nD bf16
    bfraw* xnw     = aggb + nD;               // nD bf16 (128B aligned)
    bfraw* x1w     = xnw + nD;                // nD bf16
    int*   adj     = (int*)(x1w + nD);        // nbuckets*capA ints (gapped)
    uint32* stage  = (uint32*)aggb;           // nbuckets*capS uints; spans aggb+xnw, dead
                                              // before k_normalize/k_gather write them

    const int B = 256;

    // --- CSR build (fixed-cap regions; bucket-relative cursors zeroed via memset) ---
    hipMemsetAsync(bcur, 0, NBMAX * 16 * sizeof(int), stream);
    k_bin   <<<(E + EPW - 1) / EPW, B, 0, stream>>>(ei, E, stage, bcur, shift, sbits,
                                                    capS, nbuckets);
    k_bucket<<<nbuckets, B, 0, stream>>>(stage, bcur, offsets, oendA, adj, dinv,
                                         n, shift, sbits, capS, capA);

    // --- xn -> bf16 prescaled ---
    k_normalize<<<(n + 3) / 4, B, 0, stream>>>(emb, dinv, xnw, n);

    // --- layer 1 ---
    k_gather   <<<(n + 3) / 4, B, 0, stream>>>(adj, offsets, oendA, dinv, xnw, aggb, n);
    k_linear_rt<<<(n + 63) / 64, B, 0, stream>>>(aggb, W1, b1, dinv, x1w, n);

    // --- layers 2+3 fused ---
    k_gather   <<<(n + 3) / 4, B, 0, stream>>>(adj, offsets, oendA, dinv, x1w, aggb, n);
    k_final_rt <<<(n + 63) / 64, B, 0, stream>>>(aggb, xnw, x1w, dinv, W2, b2, W3, b3, out, n);
}